// Round 1
// baseline (232.988 us; speedup 1.0000x reference)
//
#include <hip/hip_runtime.h>

#define NUM_LABELS 512
#define MIN_INTENSITY (-0.003f)
#define MAX_INTENSITY (0.003f)

// ws layout: [0..511] float sums | [512..1023] uint counts | [1024..1535] int bad
// memset first 4096 bytes (sums+counts) to 0 before accum.

__global__ __launch_bounds__(256) void accum_kernel(
    const int* __restrict__ labels,
    const float* __restrict__ vals,
    float* __restrict__ g_sum,
    unsigned int* __restrict__ g_cnt,
    int n) {
  __shared__ float s_sum[NUM_LABELS];
  __shared__ unsigned int s_cnt[NUM_LABELS];
  for (int i = threadIdx.x; i < NUM_LABELS; i += blockDim.x) {
    s_sum[i] = 0.0f;
    s_cnt[i] = 0u;
  }
  __syncthreads();

  const int n4 = n >> 2;  // vectorized portion
  const int stride = gridDim.x * blockDim.x;
  int i = blockIdx.x * blockDim.x + threadIdx.x;
  const int4* l4 = reinterpret_cast<const int4*>(labels);
  const float4* v4 = reinterpret_cast<const float4*>(vals);
  for (; i < n4; i += stride) {
    int4 l = l4[i];
    float4 v = v4[i];
    atomicAdd(&s_sum[l.x], v.x); atomicAdd(&s_cnt[l.x], 1u);
    atomicAdd(&s_sum[l.y], v.y); atomicAdd(&s_cnt[l.y], 1u);
    atomicAdd(&s_sum[l.z], v.z); atomicAdd(&s_cnt[l.z], 1u);
    atomicAdd(&s_sum[l.w], v.w); atomicAdd(&s_cnt[l.w], 1u);
  }
  // scalar tail (n not multiple of 4) — only first blocks touch it
  for (int t = (n4 << 2) + blockIdx.x * blockDim.x + threadIdx.x; t < n;
       t += stride) {
    atomicAdd(&s_sum[labels[t]], vals[t]);
    atomicAdd(&s_cnt[labels[t]], 1u);
  }
  __syncthreads();

  for (int j = threadIdx.x; j < NUM_LABELS; j += blockDim.x) {
    unsigned int c = s_cnt[j];
    if (c) {
      atomicAdd(&g_sum[j], s_sum[j]);
      atomicAdd(&g_cnt[j], c);
    }
  }
}

__global__ __launch_bounds__(NUM_LABELS) void flags_kernel(
    const float* __restrict__ g_sum,
    const unsigned int* __restrict__ g_cnt,
    int* __restrict__ bad) {
  int l = threadIdx.x;
  float c = (float)g_cnt[l];
  float mean = g_sum[l] / fmaxf(c, 1.0f);
  int b = ((mean < MIN_INTENSITY) || (mean > MAX_INTENSITY)) && (l != 0);
  bad[l] = b;
}

__global__ __launch_bounds__(256) void apply_kernel(
    const int* __restrict__ labels,
    const int* __restrict__ bad,
    int* __restrict__ out,
    int n) {
  __shared__ int s_bad[NUM_LABELS];
  for (int i = threadIdx.x; i < NUM_LABELS; i += blockDim.x)
    s_bad[i] = bad[i];
  __syncthreads();

  const int n4 = n >> 2;
  const int stride = gridDim.x * blockDim.x;
  int i = blockIdx.x * blockDim.x + threadIdx.x;
  const int4* l4 = reinterpret_cast<const int4*>(labels);
  int4* o4 = reinterpret_cast<int4*>(out);
  for (; i < n4; i += stride) {
    int4 l = l4[i];
    int4 o;
    o.x = s_bad[l.x] ? 0 : l.x;
    o.y = s_bad[l.y] ? 0 : l.y;
    o.z = s_bad[l.z] ? 0 : l.z;
    o.w = s_bad[l.w] ? 0 : l.w;
    o4[i] = o;
  }
  for (int t = (n4 << 2) + blockIdx.x * blockDim.x + threadIdx.x; t < n;
       t += stride) {
    int l = labels[t];
    out[t] = s_bad[l] ? 0 : l;
  }
}

extern "C" void kernel_launch(void* const* d_in, const int* in_sizes, int n_in,
                              void* d_out, int out_size, void* d_ws,
                              size_t ws_size, hipStream_t stream) {
  const int* labels = (const int*)d_in[0];
  const float* vals = (const float*)d_in[1];
  int* out = (int*)d_out;
  const int n = in_sizes[0];

  float* g_sum = (float*)d_ws;
  unsigned int* g_cnt = (unsigned int*)((char*)d_ws + NUM_LABELS * 4);
  int* bad = (int*)((char*)d_ws + NUM_LABELS * 8);

  // zero the accumulators (ws is poisoned 0xAA before every timed launch)
  hipMemsetAsync(d_ws, 0, NUM_LABELS * 8, stream);

  const int block = 256;
  int grid = (n / 4 + block - 1) / block;
  if (grid > 2048) grid = 2048;
  if (grid < 1) grid = 1;

  accum_kernel<<<grid, block, 0, stream>>>(labels, vals, g_sum, g_cnt, n);
  flags_kernel<<<1, NUM_LABELS, 0, stream>>>(g_sum, g_cnt, bad);
  apply_kernel<<<grid, block, 0, stream>>>(labels, bad, out, n);
}

// Round 4
// 196.482 us; speedup vs baseline: 1.1858x; 1.1858x over previous
//
#include <hip/hip_runtime.h>

#define NUM_LABELS 512
#define CNT_BITS 25
#define CNT_MASK ((1LL << CNT_BITS) - 1)
#define FXSCALE 1048576.0f  // 2^20

// Pack one sample into a single u64 histogram update:
//   high 39 bits: fixed-point sum (value * 2^20), two's complement
//   low  25 bits: count (+1 per sample). Max count 2^25-1 = 33.5M > n.
__device__ __forceinline__ unsigned long long pack1(float v) {
  long long fx = (long long)__float2int_rn(v * FXSCALE);
  return (unsigned long long)(fx * (1LL << CNT_BITS) + 1LL);
}

__global__ __launch_bounds__(256) void accum_kernel(
    const int* __restrict__ labels,
    const float* __restrict__ vals,
    unsigned long long* __restrict__ g_hist,
    int n) {
  __shared__ unsigned long long s_hist[NUM_LABELS];
  for (int i = threadIdx.x; i < NUM_LABELS; i += 256) s_hist[i] = 0ULL;
  __syncthreads();

  const int n4 = n >> 2;
  const int tid = blockIdx.x * 256 + threadIdx.x;
  const int stride = gridDim.x * 256;
  const int4* l4 = reinterpret_cast<const int4*>(labels);
  const float4* v4 = reinterpret_cast<const float4*>(vals);

  // 4-wide unrolled grid-stride loop: 8 independent 16B loads in flight
  // before any dependent LDS op.
  for (int base = tid; base < n4; base += 4 * stride) {
    const int i0 = base;
    const int i1 = base + stride;
    const int i2 = base + 2 * stride;
    const int i3 = base + 3 * stride;
    const bool p1 = i1 < n4, p2 = i2 < n4, p3 = i3 < n4;

    int4 l0 = l4[i0];
    float4 v0 = v4[i0];
    int4 l1, l2, l3;
    float4 v1, v2, v3;
    if (p1) { l1 = l4[i1]; v1 = v4[i1]; }
    if (p2) { l2 = l4[i2]; v2 = v4[i2]; }
    if (p3) { l3 = l4[i3]; v3 = v4[i3]; }

#define ACC4(L, V)                                   \
    atomicAdd(&s_hist[(L).x], pack1((V).x));         \
    atomicAdd(&s_hist[(L).y], pack1((V).y));         \
    atomicAdd(&s_hist[(L).z], pack1((V).z));         \
    atomicAdd(&s_hist[(L).w], pack1((V).w));

    ACC4(l0, v0)
    if (p1) { ACC4(l1, v1) }
    if (p2) { ACC4(l2, v2) }
    if (p3) { ACC4(l3, v3) }
#undef ACC4
  }

  // scalar tail (n % 4)
  for (int t = (n4 << 2) + tid; t < n; t += stride) {
    atomicAdd(&s_hist[labels[t]], pack1(vals[t]));
  }
  __syncthreads();

  for (int j = threadIdx.x; j < NUM_LABELS; j += 256) {
    unsigned long long h = s_hist[j];
    if (h) atomicAdd(&g_hist[j], h);
  }
}

__global__ __launch_bounds__(256) void apply_kernel(
    const int* __restrict__ labels,
    const unsigned long long* __restrict__ g_hist,
    int* __restrict__ out,
    int n) {
  __shared__ int s_bad[NUM_LABELS];
  // Every block redundantly decodes the histogram -> bad flags (4 KB from L2).
  for (int j = threadIdx.x; j < NUM_LABELS; j += 256) {
    long long p = (long long)g_hist[j];
    int cnt = (int)(p & CNT_MASK);
    long long sf = p >> CNT_BITS;  // arithmetic shift: exact fixed-point sum
    int c = cnt > 1 ? cnt : 1;
    float mean = (float)((double)sf / ((double)FXSCALE * (double)c));
    s_bad[j] = ((mean < -0.003f) || (mean > 0.003f)) && (j != 0);
  }
  __syncthreads();

  const int n4 = n >> 2;
  const int tid = blockIdx.x * 256 + threadIdx.x;
  const int stride = gridDim.x * 256;
  const int4* l4 = reinterpret_cast<const int4*>(labels);
  int4* o4 = reinterpret_cast<int4*>(out);

  for (int base = tid; base < n4; base += 4 * stride) {
    const int i0 = base;
    const int i1 = base + stride;
    const int i2 = base + 2 * stride;
    const int i3 = base + 3 * stride;
    const bool p1 = i1 < n4, p2 = i2 < n4, p3 = i3 < n4;

    int4 l0 = l4[i0];
    int4 l1, l2, l3;
    if (p1) l1 = l4[i1];
    if (p2) l2 = l4[i2];
    if (p3) l3 = l4[i3];

#define FILT(L)                                      \
    { (L).x = s_bad[(L).x] ? 0 : (L).x;              \
      (L).y = s_bad[(L).y] ? 0 : (L).y;              \
      (L).z = s_bad[(L).z] ? 0 : (L).z;              \
      (L).w = s_bad[(L).w] ? 0 : (L).w; }

    FILT(l0)
    o4[i0] = l0;
    if (p1) { FILT(l1) o4[i1] = l1; }
    if (p2) { FILT(l2) o4[i2] = l2; }
    if (p3) { FILT(l3) o4[i3] = l3; }
#undef FILT
  }

  for (int t = (n4 << 2) + tid; t < n; t += stride) {
    int l = labels[t];
    out[t] = s_bad[l] ? 0 : l;
  }
}

extern "C" void kernel_launch(void* const* d_in, const int* in_sizes, int n_in,
                              void* d_out, int out_size, void* d_ws,
                              size_t ws_size, hipStream_t stream) {
  const int* labels = (const int*)d_in[0];
  const float* vals = (const float*)d_in[1];
  int* out = (int*)d_out;
  const int n = in_sizes[0];

  unsigned long long* g_hist = (unsigned long long*)d_ws;

  // ws is re-poisoned 0xAA before every timed launch — zero the histogram.
  hipMemsetAsync(d_ws, 0, NUM_LABELS * 8, stream);

  const int block = 256;
  const int grid = 2048;  // 8 blocks/CU on 256 CUs

  accum_kernel<<<grid, block, 0, stream>>>(labels, vals, g_hist, n);
  apply_kernel<<<grid, block, 0, stream>>>(labels, g_hist, out, n);
}